// Round 5
// baseline (699.549 us; speedup 1.0000x reference)
//
#include <hip/hip_runtime.h>
#include <math.h>

#define BB   128
#define DECD 512
#define E2D  1024
#define EMBD 256
#define S1D  200
#define S2D  200
#define SJD  400
#define VV   50000
#define NEGV (-1e10f)

typedef unsigned short u16;
typedef __bf16 bf16x8 __attribute__((ext_vector_type(8)));
typedef float f32x4 __attribute__((ext_vector_type(4)));
typedef u16 u16x8 __attribute__((ext_vector_type(8)));

__device__ __forceinline__ u16 f2bf(float x) {
  unsigned u = __float_as_uint(x);
  unsigned r = (u + 0x7fffu + ((u >> 16) & 1u)) >> 16;
  return (u16)r;
}
__device__ __forceinline__ float bf2f(u16 h) {
  return __uint_as_float(((unsigned)h) << 16);
}

typedef const __attribute__((address_space(1))) void* gas_t;
typedef __attribute__((address_space(3))) void* las_t;
__device__ __forceinline__ void async_copy16(const u16* g, u16* l) {
  __builtin_amdgcn_global_load_lds((gas_t)g, (las_t)l, 16, 0, 0);
}

// ---------------- generic fp32 -> bf16 ----------------
__global__ __launch_bounds__(256) void k_cvt(const float* __restrict__ src,
    u16* __restrict__ dst, int n8) {
  int i = blockIdx.x * 256 + threadIdx.x;
  if (i >= n8) return;
  const float4 f0 = *(const float4*)(src + (size_t)i * 8);
  const float4 f1 = *(const float4*)(src + (size_t)i * 8 + 4);
  u16x8 o;
  o[0] = f2bf(f0.x); o[1] = f2bf(f0.y); o[2] = f2bf(f0.z); o[3] = f2bf(f0.w);
  o[4] = f2bf(f1.x); o[5] = f2bf(f1.y); o[6] = f2bf(f1.z); o[7] = f2bf(f1.w);
  *(u16x8*)(dst + (size_t)i * 8) = o;
}

// Wt[n][k] = bf16( W[512+k][n] )
__global__ __launch_bounds__(256) void k_wt(const float* __restrict__ W,
    u16* __restrict__ Wt) {
  __shared__ float t[32][33];
  int bk = blockIdx.x, bn = blockIdx.y;
  int tx = threadIdx.x & 31, ty = threadIdx.x >> 5;
  #pragma unroll
  for (int r = 0; r < 4; ++r) {
    int k = bk * 32 + ty + r * 8;
    t[ty + r * 8][tx] = W[(size_t)(512 + k) * 512 + bn * 32 + tx];
  }
  __syncthreads();
  #pragma unroll
  for (int r = 0; r < 4; ++r) {
    int n = bn * 32 + ty + r * 8;
    Wt[(size_t)n * 1024 + bk * 32 + tx] = f2bf(t[tx][ty + r * 8]);
  }
}

// ---------------- 8-wave fused energy GEMM, BM=64, double-buffered ----------------
// One block per 64 rows; full N=512 in-block. 8 waves = 2M x 4N, acc[2][8].
// CONV=1: A from fp32 enc (reg-staged, converted, also written to Abf_out).
// CONV=0: A from bf16 Abf_in via global_load_lds (pre-swizzled source).
template<int CONV>
__global__ __launch_bounds__(512) void gemm_energy8(
    const float* __restrict__ enc1, const float* __restrict__ enc2,
    const u16* __restrict__ Abf_in, u16* __restrict__ Abf_out,
    const u16* __restrict__ Bt,
    const float* __restrict__ hW, const float* __restrict__ v,
    float* __restrict__ scores, int sldS) {
  __shared__ u16 As[2][64 * 32];     // 2 x 4 KB
  __shared__ u16 Bs[2][512 * 32];    // 2 x 32 KB
  __shared__ float sbuf[64][4];
  int tid = threadIdx.x;
  int wid = tid >> 6, lane = tid & 63;
  int wr = wid >> 2, wc = wid & 3;       // 2M x 4N
  size_t m0 = (size_t)blockIdx.x * 64;
  int bhalf = (blockIdx.x & 1) * 64;     // batch-row offset within the 128-batch
  int sidx = blockIdx.x >> 1;

  // ---- A staging setup ----
  // CONV=1 (reg path, tid<256): rA = tid>>2 in [0,64), cslot = tid&3
  int rA = tid >> 2, cslot = tid & 3;
  const float* gA_f = nullptr;
  u16* gA_o = nullptr;
  int lAoff = rA * 32 + ((cslot ^ ((rA >> 1) & 3)) * 8);   // u16 offset, swizzled
  if (CONV) {
    const float* base = (m0 < (size_t)S1D * BB) ? (enc1 + m0 * E2D)
                                                : (enc2 + (m0 - (size_t)S1D * BB) * E2D);
    gA_f = base + (size_t)rA * E2D + cslot * 8;
    gA_o = Abf_out + (m0 + rA) * E2D + cslot * 8;
  }
  // CONV=0 (async path, wid<4): wave-uniform dest, per-lane pre-swizzled source
  const u16* gA_b = nullptr;
  if (!CONV) {
    int rowa = wid * 16 + (lane >> 2);
    int ca = (lane & 3) ^ ((rowa >> 1) & 3);
    gA_b = Abf_in + (m0 + rowa) * E2D + ca * 8;
  }

  // ---- B staging (all 8 waves, 4 issues each of 16 B/lane) ----
  const u16* gB[4]; int lBoff[4];
  #pragma unroll
  for (int i = 0; i < 4; ++i) {
    int idx = i * 512 + tid;
    int rn = idx >> 2;
    int c = (idx & 3) ^ ((rn >> 1) & 3);
    gB[i] = Bt + (size_t)rn * E2D + c * 8;
    lBoff[i] = i * 4096 + wid * 512;     // u16 offset of wave-uniform chunk
  }

  // ---- fragment LDS byte offsets ----
  int q = lane >> 4, cl = lane & 15;
  int aoff[2], boff[8];
  #pragma unroll
  for (int mi = 0; mi < 2; ++mi) {
    int row = wr * 32 + mi * 16 + cl;
    aoff[mi] = row * 64 + ((q ^ ((row >> 1) & 3)) * 16);
  }
  #pragma unroll
  for (int nj = 0; nj < 8; ++nj) {
    int rn = wc * 128 + nj * 16 + cl;
    boff[nj] = rn * 64 + ((q ^ ((rn >> 1) & 3)) * 16);
  }

  f32x4 acc[2][8];
  #pragma unroll
  for (int mi = 0; mi < 2; ++mi)
    #pragma unroll
    for (int nj = 0; nj < 8; ++nj) {
      f32x4 z = {0.f, 0.f, 0.f, 0.f};
      acc[mi][nj] = z;
    }

  // ---- prologue: stage step 0 into buf 0; prefetch regs for step 1 ----
  float4 a0, a1;
  if (CONV && tid < 256) {
    a0 = *(const float4*)(gA_f);
    a1 = *(const float4*)(gA_f + 4);
    u16x8 ob;
    ob[0] = f2bf(a0.x); ob[1] = f2bf(a0.y); ob[2] = f2bf(a0.z); ob[3] = f2bf(a0.w);
    ob[4] = f2bf(a1.x); ob[5] = f2bf(a1.y); ob[6] = f2bf(a1.z); ob[7] = f2bf(a1.w);
    *(u16x8*)(&As[0][lAoff]) = ob;
    *(u16x8*)(gA_o) = ob;
    a0 = *(const float4*)(gA_f + 32);
    a1 = *(const float4*)(gA_f + 36);
  }
  if (!CONV && wid < 4) async_copy16(gA_b, &As[0][wid * 512]);
  #pragma unroll
  for (int i = 0; i < 4; ++i) async_copy16(gB[i], &Bs[0][lBoff[i]]);
  __syncthreads();

  // ---- main loop: 32 K-steps, 2-phase double buffer ----
  for (int t = 0; t < 32; ++t) {
    int cur = t & 1, nxt = cur ^ 1;
    int k1 = (t + 1) * 32;
    if (t < 31) {
      if (CONV && tid < 256) {
        u16x8 ob;
        ob[0] = f2bf(a0.x); ob[1] = f2bf(a0.y); ob[2] = f2bf(a0.z); ob[3] = f2bf(a0.w);
        ob[4] = f2bf(a1.x); ob[5] = f2bf(a1.y); ob[6] = f2bf(a1.z); ob[7] = f2bf(a1.w);
        *(u16x8*)(&As[nxt][lAoff]) = ob;
        *(u16x8*)(gA_o + k1) = ob;
      }
      if (!CONV && wid < 4) async_copy16(gA_b + k1, &As[nxt][wid * 512]);
      #pragma unroll
      for (int i = 0; i < 4; ++i) async_copy16(gB[i] + k1, &Bs[nxt][lBoff[i]]);
      if (CONV && t < 30 && tid < 256) {     // prefetch regs for step t+2
        a0 = *(const float4*)(gA_f + k1 + 32);
        a1 = *(const float4*)(gA_f + k1 + 36);
      }
    }
    bf16x8 af[2], bg[8];
    #pragma unroll
    for (int mi = 0; mi < 2; ++mi)
      af[mi] = *(const bf16x8*)((const char*)As[cur] + aoff[mi]);
    #pragma unroll
    for (int nj = 0; nj < 8; ++nj)
      bg[nj] = *(const bf16x8*)((const char*)Bs[cur] + boff[nj]);
    #pragma unroll
    for (int mi = 0; mi < 2; ++mi)
      #pragma unroll
      for (int nj = 0; nj < 8; ++nj)
        acc[mi][nj] = __builtin_amdgcn_mfma_f32_16x16x32_bf16(af[mi], bg[nj], acc[mi][nj], 0, 0, 0);
    __syncthreads();
  }

  // ---- epilogue: sum_d tanh(acc + hW)*v ----
  #pragma unroll
  for (int mi = 0; mi < 2; ++mi) {
    #pragma unroll
    for (int j = 0; j < 4; ++j) {
      int m = wr * 32 + mi * 16 + q * 4 + j;      // local row 0..63
      float s = 0.f;
      #pragma unroll
      for (int nj = 0; nj < 8; ++nj) {
        int d = wc * 128 + nj * 16 + cl;
        s += tanhf(acc[mi][nj][j] + hW[(size_t)(bhalf + m) * DECD + d]) * v[d];
      }
      s += __shfl_xor(s, 1, 64);
      s += __shfl_xor(s, 2, 64);
      s += __shfl_xor(s, 4, 64);
      s += __shfl_xor(s, 8, 64);
      if (cl == 0) sbuf[m][wc] = s;
    }
  }
  __syncthreads();
  if (tid < 64)
    scores[(size_t)(bhalf + tid) * sldS + sidx] =
        sbuf[tid][0] + sbuf[tid][1] + sbuf[tid][2] + sbuf[tid][3];
}

// ---------------- MFMA A@B^T with fused fp32->bf16 of B, 2-deep B pipeline ----------------
__global__ __launch_bounds__(256) void gemm_fc(
    const u16* __restrict__ A, const float* __restrict__ Bf,
    const float* __restrict__ bias, float* __restrict__ C,
    int N, int K) {
  __shared__ u16 As[128 * 32];
  __shared__ u16 Bs[64 * 32];
  int tid = threadIdx.x;
  int wid = tid >> 6, lane = tid & 63;
  int wr = wid >> 1, wc = wid & 1;
  int n0 = blockIdx.x * 64;

  int idx0 = tid, idx1 = tid + 256;
  int rA0 = idx0 >> 2, cA0 = (idx0 & 3) ^ ((rA0 >> 1) & 3);
  int rA1 = idx1 >> 2, cA1 = (idx1 & 3) ^ ((rA1 >> 1) & 3);
  const u16* gA0 = A + (size_t)rA0 * K + cA0 * 8;
  const u16* gA1 = A + (size_t)rA1 * K + cA1 * 8;
  u16* lA0 = As + wid * 512;
  u16* lA1 = As + 2048 + wid * 512;

  int rB = tid >> 2, cB = tid & 3;
  int gnB = n0 + rB; if (gnB >= N) gnB = N - 1;
  const float* gB = Bf + (size_t)gnB * K + cB * 8;
  u16* lBp = Bs + rB * 32 + (cB ^ ((rB >> 1) & 3)) * 8;

  int q = lane >> 4, cl = lane & 15;
  int aoff[4], boff[2];
  #pragma unroll
  for (int mi = 0; mi < 4; ++mi) {
    int row = wr * 64 + mi * 16 + cl;
    aoff[mi] = row * 64 + ((q ^ ((row >> 1) & 3)) * 16);
  }
  #pragma unroll
  for (int nj = 0; nj < 2; ++nj) {
    int rn = wc * 32 + nj * 16 + cl;
    boff[nj] = rn * 64 + ((q ^ ((rn >> 1) & 3)) * 16);
  }

  f32x4 acc[4][2];
  #pragma unroll
  for (int mi = 0; mi < 4; ++mi)
    #pragma unroll
    for (int nj = 0; nj < 2; ++nj) {
      f32x4 z = {0.f, 0.f, 0.f, 0.f};
      acc[mi][nj] = z;
    }

  float4 p0 = *(const float4*)(gB),      p1 = *(const float4*)(gB + 4);
  float4 q0 = *(const float4*)(gB + 32), q1 = *(const float4*)(gB + 36);

  for (int k0 = 0; k0 < K; k0 += 64) {
    {
      u16x8 ob;
      ob[0] = f2bf(p0.x); ob[1] = f2bf(p0.y); ob[2] = f2bf(p0.z); ob[3] = f2bf(p0.w);
      ob[4] = f2bf(p1.x); ob[5] = f2bf(p1.y); ob[6] = f2bf(p1.z); ob[7] = f2bf(p1.w);
      *(u16x8*)lBp = ob;
      async_copy16(gA0 + k0, lA0);
      async_copy16(gA1 + k0, lA1);
      __syncthreads();
      if (k0 + 64 < K) { p0 = *(const float4*)(gB + k0 + 64); p1 = *(const float4*)(gB + k0 + 68); }
      bf16x8 af[4], bg[2];
      #pragma unroll
      for (int mi = 0; mi < 4; ++mi) af[mi] = *(const bf16x8*)((const char*)As + aoff[mi]);
      #pragma unroll
      for (int nj = 0; nj < 2; ++nj) bg[nj] = *(const bf16x8*)((const char*)Bs + boff[nj]);
      #pragma unroll
      for (int mi = 0; mi < 4; ++mi)
        #pragma unroll
        for (int nj = 0; nj < 2; ++nj)
          acc[mi][nj] = __builtin_amdgcn_mfma_f32_16x16x32_bf16(af[mi], bg[nj], acc[mi][nj], 0, 0, 0);
      __syncthreads();
    }
    {
      u16x8 ob;
      ob[0] = f2bf(q0.x); ob[1] = f2bf(q0.y); ob[2] = f2bf(q0.z); ob[3] = f2bf(q0.w);
      ob[4] = f2bf(q1.x); ob[5] = f2bf(q1.y); ob[6] = f2bf(q1.z); ob[7] = f2bf(q1.w);
      *(u16x8*)lBp = ob;
      async_copy16(gA0 + k0 + 32, lA0);
      async_copy16(gA1 + k0 + 32, lA1);
      __syncthreads();
      if (k0 + 96 < K) { q0 = *(const float4*)(gB + k0 + 96); q1 = *(const float4*)(gB + k0 + 100); }
      bf16x8 af[4], bg[2];
      #pragma unroll
      for (int mi = 0; mi < 4; ++mi) af[mi] = *(const bf16x8*)((const char*)As + aoff[mi]);
      #pragma unroll
      for (int nj = 0; nj < 2; ++nj) bg[nj] = *(const bf16x8*)((const char*)Bs + boff[nj]);
      #pragma unroll
      for (int mi = 0; mi < 4; ++mi)
        #pragma unroll
        for (int nj = 0; nj < 2; ++nj)
          acc[mi][nj] = __builtin_amdgcn_mfma_f32_16x16x32_bf16(af[mi], bg[nj], acc[mi][nj], 0, 0, 0);
      __syncthreads();
    }
  }

  #pragma unroll
  for (int mi = 0; mi < 4; ++mi) {
    #pragma unroll
    for (int nj = 0; nj < 2; ++nj) {
      int n = n0 + wc * 32 + nj * 16 + cl;
      if (n < N) {
        float bv = bias[n];
        #pragma unroll
        for (int j = 0; j < 4; ++j) {
          int m = wr * 64 + mi * 16 + q * 4 + j;
          C[(size_t)m * N + n] = acc[mi][nj][j] + bv;
        }
      }
    }
  }
}

// ---------------- small kernels ----------------
__global__ __launch_bounds__(256) void k_partial(const float* __restrict__ h,
    const float* __restrict__ W, const float* __restrict__ bias,
    float* __restrict__ out) {
  int b = blockIdx.y;
  int d = blockIdx.x * 256 + threadIdx.x;
  const float* hr = h + (size_t)b * DECD;
  float acc = bias[d];
  #pragma unroll 8
  for (int k = 0; k < DECD; ++k) acc += hr[k] * W[(size_t)k * DECD + d];
  out[(size_t)b * DECD + d] = acc;
}

__global__ __launch_bounds__(256) void k_softmax_s(float* __restrict__ sc, int S,
    const int* __restrict__ m1, const int* __restrict__ m2, int mode) {
  int b = blockIdx.x, tid = threadIdx.x;
  __shared__ float sm[4];
  int s0 = tid, s2 = tid + 256;
  float a0 = -INFINITY, a1 = -INFINITY;
  if (s0 < S) {
    int msk = (mode == 0) ? ((s0 < S1D) ? m1[b * S1D + s0] : m2[b * S2D + (s0 - S1D)])
                          : (m1[b * S1D + s0] * m2[b * S1D + s0]);
    a0 = msk ? sc[(size_t)b * S + s0] : NEGV;
  }
  if (s2 < S) {
    int msk = (mode == 0) ? ((s2 < S1D) ? m1[b * S1D + s2] : m2[b * S2D + (s2 - S1D)])
                          : (m1[b * S1D + s2] * m2[b * S1D + s2]);
    a1 = msk ? sc[(size_t)b * S + s2] : NEGV;
  }
  float vmax = fmaxf(a0, a1);
  #pragma unroll
  for (int off = 32; off > 0; off >>= 1) vmax = fmaxf(vmax, __shfl_down(vmax, off, 64));
  int lane = tid & 63, wid = tid >> 6;
  if (lane == 0) sm[wid] = vmax;
  __syncthreads();
  vmax = fmaxf(fmaxf(sm[0], sm[1]), fmaxf(sm[2], sm[3]));
  __syncthreads();
  float lsum = 0.f;
  if (s0 < S) lsum += expf(a0 - vmax);
  if (s2 < S) lsum += expf(a1 - vmax);
  #pragma unroll
  for (int off = 32; off > 0; off >>= 1) lsum += __shfl_down(lsum, off, 64);
  if (lane == 0) sm[wid] = lsum;
  __syncthreads();
  float inv = 1.0f / (sm[0] + sm[1] + sm[2] + sm[3]);
  if (s0 < S) sc[(size_t)b * S + s0] = expf(a0 - vmax) * inv;
  if (s2 < S) sc[(size_t)b * S + s2] = expf(a1 - vmax) * inv;
}

__global__ __launch_bounds__(256) void k_wpart(const u16* __restrict__ A,
    const float* __restrict__ a, float* __restrict__ wp) {
  int b = blockIdx.x;
  int e2 = blockIdx.y * 256 + threadIdx.x;
  int scn = blockIdx.z;
  const float* arow = a + (size_t)b * SJD;
  float acc0 = 0.f, acc1 = 0.f;
  #pragma unroll 4
  for (int s = scn * 100; s < scn * 100 + 100; ++s) {
    unsigned u = *(const unsigned*)(A + ((size_t)s * BB + b) * E2D + e2 * 2);
    float w = arow[s];
    acc0 += w * bf2f((u16)(u & 0xffff));
    acc1 += w * bf2f((u16)(u >> 16));
  }
  float* dst = wp + ((size_t)scn * BB + b) * E2D + e2 * 2;
  dst[0] = acc0;
  dst[1] = acc1;
}

__global__ __launch_bounds__(256) void k_wsum_x(const float* __restrict__ wp,
    float* __restrict__ wgt, u16* __restrict__ x) {
  int i = blockIdx.x * 256 + threadIdx.x;
  const int NN = BB * E2D;
  float s = wp[i] + wp[NN + i] + wp[2 * NN + i] + wp[3 * NN + i];
  wgt[i] = s;
  int b = i >> 10, e = i & 1023;
  x[(size_t)b * 1280 + EMBD + e] = f2bf(s);
}

__global__ __launch_bounds__(256) void k_embx(const int* __restrict__ inp,
    const float* __restrict__ table, u16* __restrict__ x) {
  int b = blockIdx.x, t = threadIdx.x;
  x[(size_t)b * 1280 + t] = f2bf(table[(size_t)inp[b] * EMBD + t]);
}

__global__ __launch_bounds__(256) void k_concat_state_bf(const float* __restrict__ hnew,
    const float* __restrict__ wgt, u16* __restrict__ st) {
  int b = blockIdx.x;
  for (int i = threadIdx.x; i < DECD + E2D; i += 256) {
    float vv = (i < DECD) ? hnew[(size_t)b * DECD + i] : wgt[(size_t)b * E2D + i - DECD];
    st[(size_t)b * (DECD + E2D) + i] = f2bf(vv);
  }
}

__global__ __launch_bounds__(256) void k_gru(const float* __restrict__ gx,
    const float* __restrict__ gh, const float* __restrict__ hidden,
    float* __restrict__ hnew) {
  int b = blockIdx.x, tid = threadIdx.x;
  #pragma unroll
  for (int qq = 0; qq < 2; ++qq) {
    int d = tid + qq * 256;
    size_t o = (size_t)b * 1536;
    float xr = gx[o + d],        hr = gh[o + d];
    float xz = gx[o + 512 + d],  hz = gh[o + 512 + d];
    float xn = gx[o + 1024 + d], hn = gh[o + 1024 + d];
    float r = 1.f / (1.f + expf(-(xr + hr)));
    float z = 1.f / (1.f + expf(-(xz + hz)));
    float n = tanhf(xn + r * hn);
    hnew[(size_t)b * DECD + d] = (1.f - z) * n + z * hidden[(size_t)b * DECD + d];
  }
}

__global__ __launch_bounds__(256) void k_pgen(const float* __restrict__ wgt,
    const int* __restrict__ inp, const float* __restrict__ table,
    const float* __restrict__ gW, const float* __restrict__ gb,
    float* __restrict__ pg) {
  int b = blockIdx.x, tid = threadIdx.x;
  __shared__ float sm[4];
  float s = 0.f;
  for (int k = tid; k < E2D + EMBD; k += 256)
    s += gW[k] * ((k < E2D) ? wgt[(size_t)b * E2D + k]
                            : table[(size_t)inp[b] * EMBD + k - E2D]);
  #pragma unroll
  for (int off = 32; off > 0; off >>= 1) s += __shfl_down(s, off, 64);
  int lane = tid & 63, wid = tid >> 6;
  if (lane == 0) sm[wid] = s;
  __syncthreads();
  if (tid == 0) {
    float t = sm[0] + sm[1] + sm[2] + sm[3] + gb[0];
    pg[b] = 1.f / (1.f + expf(-t));
  }
}

__global__ __launch_bounds__(256) void k_vocab(float* __restrict__ dist,
    const float* __restrict__ pg) {
  int b = blockIdx.x, tid = threadIdx.x;
  float* row = dist + (size_t)b * VV;
  __shared__ float sm[4];
  float m = -INFINITY;
  for (int i = tid; i < VV; i += 256) m = fmaxf(m, row[i]);
  #pragma unroll
  for (int off = 32; off > 0; off >>= 1) m = fmaxf(m, __shfl_down(m, off, 64));
  int lane = tid & 63, wid = tid >> 6;
  if (lane == 0) sm[wid] = m;
  __syncthreads();
  m = fmaxf(fmaxf(sm[0], sm[1]), fmaxf(sm[2], sm[3]));
  __syncthreads();
  float s = 0.f;
  for (int i = tid; i < VV; i += 256) s += expf(row[i] - m);
  #pragma unroll
  for (int off = 32; off > 0; off >>= 1) s += __shfl_down(s, off, 64);
  if (lane == 0) sm[wid] = s;
  __syncthreads();
  s = sm[0] + sm[1] + sm[2] + sm[3];
  float scale = pg[b] / s;
  for (int i = tid; i < VV; i += 256) row[i] = expf(row[i] - m) * scale;
}

__global__ __launch_bounds__(256) void k_scatter(float* __restrict__ dist,
    const float* __restrict__ ad, const float* __restrict__ pg,
    const int* __restrict__ src1) {
  int b = blockIdx.x, tid = threadIdx.x;
  if (tid < S1D) {
    float val = (1.f - pg[b]) * ad[(size_t)b * S1D + tid];
    int tok = src1[(size_t)tid * BB + b];
    atomicAdd(&dist[(size_t)b * VV + tok], val);
  }
}

extern "C" void kernel_launch(void* const* d_in, const int* in_sizes, int n_in,
                              void* d_out, int out_size, void* d_ws, size_t ws_size,
                              hipStream_t stream) {
  (void)in_sizes; (void)n_in; (void)out_size; (void)ws_size;
  const int*   input  = (const int*)d_in[0];
  const float* hidden = (const float*)d_in[1];
  const int*   src1   = (const int*)d_in[2];
  const float* enc1   = (const float*)d_in[3];
  const int*   mask1  = (const int*)d_in[4];
  const int*   triple = (const int*)d_in[5];
  const float* enc2   = (const float*)d_in[6];
  const int*   mask2  = (const int*)d_in[7];
  const float* embedding = (const float*)d_in[8];
  const float* attn_W = (const float*)d_in[9];
  const float* attn_b = (const float*)d_in[10];
  const float* attn_v = (const float*)d_in[11];
  const float* copy_W = (const float*)d_in[12];
  const float* copy_b = (const float*)d_in[13];
  const float* copy_v = (const float*)d_in[14];
  const float* gru_Wih = (const float*)d_in[15];
  const float* gru_Whh = (const float*)d_in[16];
  const float* gru_bih = (const float*)d_in[17];
  const float* gru_bhh = (const float*)d_in[18];
  const float* fc_W   = (const float*)d_in[19];
  const float* fc_b   = (const float*)d_in[20];
  const float* gate_W = (const float*)d_in[21];
  const float* gate_b = (const float*)d_in[22];

  char* w = (char*)d_ws;
  u16* A_bf = (u16*)w;                w += (size_t)51200 * 1024 * 2;
  u16* Wt_a = (u16*)w;                w += (size_t)512 * 1024 * 2;
  u16* Wt_c = (u16*)w;                w += (size_t)512 * 1024 * 2;
  float* hWa  = (float*)w;            w += (size_t)BB * DECD * 4;
  float* hWc  = (float*)w;            w += (size_t)BB * DECD * 4;
  float* scJ  = (float*)w;            w += (size_t)BB * SJD * 4;
  float* scC  = (float*)w;            w += (size_t)BB * S1D * 4;
  float* wgt  = (float*)w;            w += (size_t)BB * E2D * 4;
  float* wpart = (float*)w;           w += (size_t)4 * BB * E2D * 4;
  u16*   x_bf = (u16*)w;              w += (size_t)BB * 1280 * 2;
  u16*   hid_bf = (u16*)w;            w += (size_t)BB * DECD * 2;
  float* gx   = (float*)w;            w += (size_t)BB * 1536 * 4;
  float* gh   = (float*)w;            w += (size_t)BB * 1536 * 4;
  u16*   st_bf = (u16*)w;             w += (size_t)BB * 1536 * 2;
  float* pg   = (float*)w;            w += 512;

  float* out  = (float*)d_out;
  float* hnew = out + (size_t)BB * VV;

  // prep
  k_wt<<<dim3(32, 16), 256, 0, stream>>>(attn_W, Wt_a);
  k_wt<<<dim3(32, 16), 256, 0, stream>>>(copy_W, Wt_c);
  k_cvt<<<32, 256, 0, stream>>>(hidden, hid_bf, BB * DECD / 8);
  k_partial<<<dim3(2, BB), 256, 0, stream>>>(hidden, attn_W, attn_b, hWa);
  k_embx<<<BB, 256, 0, stream>>>(input, embedding, x_bf);

  // joint attention scores (+ enc -> bf16 conversion side effect)
  gemm_energy8<1><<<SJD * 2, 512, 0, stream>>>(enc1, enc2, nullptr, A_bf, Wt_a, hWa, attn_v, scJ, SJD);
  k_softmax_s<<<BB, 256, 0, stream>>>(scJ, SJD, mask1, mask2, 0);

  // weighted context
  k_wpart<<<dim3(BB, 2, 4), 256, 0, stream>>>(A_bf, scJ, wpart);
  k_wsum_x<<<512, 256, 0, stream>>>(wpart, wgt, x_bf);

  // GRU (bf16 MFMA with fused weight conversion)
  gemm_fc<<<1536 / 64, 256, 0, stream>>>(x_bf, gru_Wih, gru_bih, gx, 1536, 1280);
  gemm_fc<<<1536 / 64, 256, 0, stream>>>(hid_bf, gru_Whh, gru_bhh, gh, 1536, 512);
  k_gru<<<BB, 256, 0, stream>>>(gx, gh, hidden, hnew);

  // vocab logits
  k_concat_state_bf<<<BB, 256, 0, stream>>>(hnew, wgt, st_bf);
  gemm_fc<<<(VV + 63) / 64, 256, 0, stream>>>(st_bf, fc_W, fc_b, out, VV, 1536);

  // copy path
  k_pgen<<<BB, 256, 0, stream>>>(wgt, input, embedding, gate_W, gate_b, pg);
  k_partial<<<dim3(2, BB), 256, 0, stream>>>(hnew, copy_W, copy_b, hWc);
  gemm_energy8<0><<<S1D * 2, 512, 0, stream>>>(nullptr, nullptr, A_bf, nullptr, Wt_c, hWc, copy_v, scC, S1D);
  k_softmax_s<<<BB, 256, 0, stream>>>(scC, S1D, mask1, triple, 1);

  // final distribution
  k_vocab<<<BB, 256, 0, stream>>>(out, pg);
  k_scatter<<<BB, 256, 0, stream>>>(out, scC, pg, src1);
}

// Round 6
// 645.357 us; speedup vs baseline: 1.0840x; 1.0840x over previous
//
#include <hip/hip_runtime.h>
#include <math.h>

#define BB   128
#define DECD 512
#define E2D  1024
#define EMBD 256
#define S1D  200
#define S2D  200
#define SJD  400
#define VV   50000
#define NEGV (-1e10f)

typedef unsigned short u16;
typedef __bf16 bf16x8 __attribute__((ext_vector_type(8)));
typedef float f32x4 __attribute__((ext_vector_type(4)));
typedef u16 u16x8 __attribute__((ext_vector_type(8)));

__device__ __forceinline__ u16 f2bf(float x) {
  unsigned u = __float_as_uint(x);
  unsigned r = (u + 0x7fffu + ((u >> 16) & 1u)) >> 16;
  return (u16)r;
}
__device__ __forceinline__ float bf2f(u16 h) {
  return __uint_as_float(((unsigned)h) << 16);
}

typedef const __attribute__((address_space(1))) void* gas_t;
typedef __attribute__((address_space(3))) void* las_t;
__device__ __forceinline__ void async_copy16(const u16* g, u16* l) {
  __builtin_amdgcn_global_load_lds((gas_t)g, (las_t)l, 16, 0, 0);
}

// ---------------- generic fp32 -> bf16 ----------------
__global__ __launch_bounds__(256) void k_cvt(const float* __restrict__ src,
    u16* __restrict__ dst, int n8) {
  int i = blockIdx.x * 256 + threadIdx.x;
  if (i >= n8) return;
  const float4 f0 = *(const float4*)(src + (size_t)i * 8);
  const float4 f1 = *(const float4*)(src + (size_t)i * 8 + 4);
  u16x8 o;
  o[0] = f2bf(f0.x); o[1] = f2bf(f0.y); o[2] = f2bf(f0.z); o[3] = f2bf(f0.w);
  o[4] = f2bf(f1.x); o[5] = f2bf(f1.y); o[6] = f2bf(f1.z); o[7] = f2bf(f1.w);
  *(u16x8*)(dst + (size_t)i * 8) = o;
}

// Wt[n][k] = bf16( W[512+k][n] )
__global__ __launch_bounds__(256) void k_wt(const float* __restrict__ W,
    u16* __restrict__ Wt) {
  __shared__ float t[32][33];
  int bk = blockIdx.x, bn = blockIdx.y;
  int tx = threadIdx.x & 31, ty = threadIdx.x >> 5;
  #pragma unroll
  for (int r = 0; r < 4; ++r) {
    int k = bk * 32 + ty + r * 8;
    t[ty + r * 8][tx] = W[(size_t)(512 + k) * 512 + bn * 32 + tx];
  }
  __syncthreads();
  #pragma unroll
  for (int r = 0; r < 4; ++r) {
    int n = bn * 32 + ty + r * 8;
    Wt[(size_t)n * 1024 + bk * 32 + tx] = f2bf(t[tx][ty + r * 8]);
  }
}

// ---------------- 4-wave fused energy GEMM, tile 64x256, N-split 2 ----------------
// grid = (2, M/64): blockIdx.x = n-half (so the pair shares A reads temporally),
// blockIdx.y = m-tile. 4 waves = 2M x 2N, acc[2][8] (64 regs).
// A: 2x4KB double-buffered LDS; B: 16KB single-buffered (256 rows x 32 k).
// CONV=1: A from fp32 enc (reg-convert), write-back to Abf_out when n-half==0.
// CONV=0: A from bf16 Abf_in via global_load_lds (pre-swizzled source).
// Output: part[bn*M + m] = sum over this n-half's 256 d of tanh(pre+hW)*v.
template<int CONV>
__global__ __launch_bounds__(256) void gemm_energy4(
    const float* __restrict__ enc1, const float* __restrict__ enc2,
    const u16* __restrict__ Abf_in, u16* __restrict__ Abf_out,
    const u16* __restrict__ Bt,
    const float* __restrict__ hW, const float* __restrict__ v,
    float* __restrict__ part, int M) {
  __shared__ u16 As[2][64 * 32];   // 2 x 4 KB
  __shared__ u16 Bs[256 * 32];     // 16 KB
  __shared__ float sbuf[64][2];
  int tid = threadIdx.x;
  int wid = tid >> 6, lane = tid & 63;
  int wr = wid >> 1, wc = wid & 1;
  int bn = blockIdx.x;                 // n-half: 0 or 1
  size_t m0 = (size_t)blockIdx.y * 64;
  int bhalf = (blockIdx.y & 1) * 64;   // batch-row offset within the 128-batch
  int n0 = bn * 256;

  // ---- A staging setup ----
  int rA = tid >> 2, cslot = tid & 3;            // 64 rows x 4 chunks
  const float* gA_f = nullptr;
  u16* gA_o = nullptr;
  int lAoff = rA * 32 + ((cslot ^ ((rA >> 1) & 3)) * 8);   // u16 offset, swizzled
  if (CONV) {
    const float* base = (m0 < (size_t)S1D * BB) ? (enc1 + m0 * E2D)
                                                : (enc2 + (m0 - (size_t)S1D * BB) * E2D);
    gA_f = base + (size_t)rA * E2D + cslot * 8;
    if (bn == 0) gA_o = Abf_out + (m0 + rA) * E2D + cslot * 8;
  }
  const u16* gA_b = nullptr;
  if (!CONV) {
    // async dest = As[buf] + wid*512 (u16) + lane*8 -> row = wid*16 + (lane>>2)
    int rowa = wid * 16 + (lane >> 2);
    int ca = (lane & 3) ^ ((rowa >> 1) & 3);
    gA_b = Abf_in + (m0 + rowa) * E2D + ca * 8;
  }

  // ---- B staging: 4 async issues; issue i dest rows [i*64 + wid*16, +16) ----
  const u16* gB[4];
  #pragma unroll
  for (int i = 0; i < 4; ++i) {
    int rn = i * 64 + wid * 16 + (lane >> 2);
    int c = (lane & 3) ^ ((rn >> 1) & 3);
    gB[i] = Bt + (size_t)(n0 + rn) * E2D + c * 8;
  }

  // ---- fragment LDS byte offsets ----
  int q = lane >> 4, cl = lane & 15;
  int aoff[2], boff[8];
  #pragma unroll
  for (int mi = 0; mi < 2; ++mi) {
    int row = wr * 32 + mi * 16 + cl;
    aoff[mi] = row * 64 + ((q ^ ((row >> 1) & 3)) * 16);
  }
  #pragma unroll
  for (int nj = 0; nj < 8; ++nj) {
    int rn = wc * 128 + nj * 16 + cl;
    boff[nj] = rn * 64 + ((q ^ ((rn >> 1) & 3)) * 16);
  }

  f32x4 acc[2][8];
  #pragma unroll
  for (int mi = 0; mi < 2; ++mi)
    #pragma unroll
    for (int nj = 0; nj < 8; ++nj) {
      f32x4 z = {0.f, 0.f, 0.f, 0.f};
      acc[mi][nj] = z;
    }

  // ---- prologue: stage A step 0 into As[0]; prep regs for step 1 ----
  float4 a0, a1;
  if (CONV) {
    a0 = *(const float4*)(gA_f);
    a1 = *(const float4*)(gA_f + 4);
    u16x8 ob;
    ob[0] = f2bf(a0.x); ob[1] = f2bf(a0.y); ob[2] = f2bf(a0.z); ob[3] = f2bf(a0.w);
    ob[4] = f2bf(a1.x); ob[5] = f2bf(a1.y); ob[6] = f2bf(a1.z); ob[7] = f2bf(a1.w);
    *(u16x8*)(&As[0][lAoff]) = ob;
    if (bn == 0) *(u16x8*)(gA_o) = ob;
    a0 = *(const float4*)(gA_f + 32);
    a1 = *(const float4*)(gA_f + 36);
  } else {
    async_copy16(gA_b, &As[0][wid * 512]);
  }

  // ---- main loop: 32 K-steps; A dbuf, B single-buffer, 2 barriers/step ----
  for (int t = 0; t < 32; ++t) {
    int cur = t & 1, nxt = cur ^ 1;
    int k0 = t * 32, k1 = k0 + 32;
    // stage B for this step
    #pragma unroll
    for (int i = 0; i < 4; ++i) async_copy16(gB[i] + k0, &Bs[2048 * i + wid * 512]);
    // stage A for next step
    if (t < 31) {
      if (CONV) {
        u16x8 ob;
        ob[0] = f2bf(a0.x); ob[1] = f2bf(a0.y); ob[2] = f2bf(a0.z); ob[3] = f2bf(a0.w);
        ob[4] = f2bf(a1.x); ob[5] = f2bf(a1.y); ob[6] = f2bf(a1.z); ob[7] = f2bf(a1.w);
        *(u16x8*)(&As[nxt][lAoff]) = ob;
        if (bn == 0) *(u16x8*)(gA_o + k1) = ob;
        if (t < 30) {                       // prefetch regs for step t+2
          a0 = *(const float4*)(gA_f + k1 + 32);
          a1 = *(const float4*)(gA_f + k1 + 36);
        }
      } else {
        async_copy16(gA_b + k1, &As[nxt][wid * 512]);
      }
    }
    __syncthreads();   // B (and next-A) staged & visible
    bf16x8 af[2];
    #pragma unroll
    for (int mi = 0; mi < 2; ++mi)
      af[mi] = *(const bf16x8*)((const char*)As[cur] + aoff[mi]);
    #pragma unroll
    for (int nj = 0; nj < 8; ++nj) {
      bf16x8 bg = *(const bf16x8*)((const char*)Bs + boff[nj]);
      acc[0][nj] = __builtin_amdgcn_mfma_f32_16x16x32_bf16(af[0], bg, acc[0][nj], 0, 0, 0);
      acc[1][nj] = __builtin_amdgcn_mfma_f32_16x16x32_bf16(af[1], bg, acc[1][nj], 0, 0, 0);
    }
    __syncthreads();   // readers done before next-step B overwrite
  }

  // ---- epilogue: partial over this n-half's 256 d ----
  #pragma unroll
  for (int mi = 0; mi < 2; ++mi) {
    #pragma unroll
    for (int j = 0; j < 4; ++j) {
      int m = wr * 32 + mi * 16 + q * 4 + j;      // local row 0..63
      float s = 0.f;
      #pragma unroll
      for (int nj = 0; nj < 8; ++nj) {
        int d = n0 + wc * 128 + nj * 16 + cl;
        s += tanhf(acc[mi][nj][j] + hW[(size_t)(bhalf + m) * DECD + d]) * v[d];
      }
      s += __shfl_xor(s, 1, 64);
      s += __shfl_xor(s, 2, 64);
      s += __shfl_xor(s, 4, 64);
      s += __shfl_xor(s, 8, 64);
      if (cl == 0) sbuf[m][wc] = s;
    }
  }
  __syncthreads();
  if (tid < 64)
    part[(size_t)bn * M + m0 + tid] = sbuf[tid][0] + sbuf[tid][1];
}

// scores[b][s] = part_half0[m] + part_half1[m], m = s*128 + b
__global__ __launch_bounds__(256) void k_sum2(const float* __restrict__ part,
    float* __restrict__ sc, int M, int S) {
  int m = blockIdx.x * 256 + threadIdx.x;
  if (m >= M) return;
  int b = m & 127, s = m >> 7;
  sc[(size_t)b * S + s] = part[m] + part[M + m];
}

// ---------------- MFMA A@B^T with fused fp32->bf16 of B, 2-deep B pipeline ----------------
__global__ __launch_bounds__(256) void gemm_fc(
    const u16* __restrict__ A, const float* __restrict__ Bf,
    const float* __restrict__ bias, float* __restrict__ C,
    int N, int K) {
  __shared__ u16 As[128 * 32];
  __shared__ u16 Bs[64 * 32];
  int tid = threadIdx.x;
  int wid = tid >> 6, lane = tid & 63;
  int wr = wid >> 1, wc = wid & 1;
  int n0 = blockIdx.x * 64;

  int idx0 = tid, idx1 = tid + 256;
  int rA0 = idx0 >> 2, cA0 = (idx0 & 3) ^ ((rA0 >> 1) & 3);
  int rA1 = idx1 >> 2, cA1 = (idx1 & 3) ^ ((rA1 >> 1) & 3);
  const u16* gA0 = A + (size_t)rA0 * K + cA0 * 8;
  const u16* gA1 = A + (size_t)rA1 * K + cA1 * 8;
  u16* lA0 = As + wid * 512;
  u16* lA1 = As + 2048 + wid * 512;

  int rB = tid >> 2, cB = tid & 3;
  int gnB = n0 + rB; if (gnB >= N) gnB = N - 1;
  const float* gB = Bf + (size_t)gnB * K + cB * 8;
  u16* lBp = Bs + rB * 32 + (cB ^ ((rB >> 1) & 3)) * 8;

  int q = lane >> 4, cl = lane & 15;
  int aoff[4], boff[2];
  #pragma unroll
  for (int mi = 0; mi < 4; ++mi) {
    int row = wr * 64 + mi * 16 + cl;
    aoff[mi] = row * 64 + ((q ^ ((row >> 1) & 3)) * 16);
  }
  #pragma unroll
  for (int nj = 0; nj < 2; ++nj) {
    int rn = wc * 32 + nj * 16 + cl;
    boff[nj] = rn * 64 + ((q ^ ((rn >> 1) & 3)) * 16);
  }

  f32x4 acc[4][2];
  #pragma unroll
  for (int mi = 0; mi < 4; ++mi)
    #pragma unroll
    for (int nj = 0; nj < 2; ++nj) {
      f32x4 z = {0.f, 0.f, 0.f, 0.f};
      acc[mi][nj] = z;
    }

  float4 p0 = *(const float4*)(gB),      p1 = *(const float4*)(gB + 4);
  float4 q0 = *(const float4*)(gB + 32), q1 = *(const float4*)(gB + 36);

  for (int k0 = 0; k0 < K; k0 += 64) {
    {
      u16x8 ob;
      ob[0] = f2bf(p0.x); ob[1] = f2bf(p0.y); ob[2] = f2bf(p0.z); ob[3] = f2bf(p0.w);
      ob[4] = f2bf(p1.x); ob[5] = f2bf(p1.y); ob[6] = f2bf(p1.z); ob[7] = f2bf(p1.w);
      *(u16x8*)lBp = ob;
      async_copy16(gA0 + k0, lA0);
      async_copy16(gA1 + k0, lA1);
      __syncthreads();
      if (k0 + 64 < K) { p0 = *(const float4*)(gB + k0 + 64); p1 = *(const float4*)(gB + k0 + 68); }
      bf16x8 af[4], bg[2];
      #pragma unroll
      for (int mi = 0; mi < 4; ++mi) af[mi] = *(const bf16x8*)((const char*)As + aoff[mi]);
      #pragma unroll
      for (int nj = 0; nj < 2; ++nj) bg[nj] = *(const bf16x8*)((const char*)Bs + boff[nj]);
      #pragma unroll
      for (int mi = 0; mi < 4; ++mi)
        #pragma unroll
        for (int nj = 0; nj < 2; ++nj)
          acc[mi][nj] = __builtin_amdgcn_mfma_f32_16x16x32_bf16(af[mi], bg[nj], acc[mi][nj], 0, 0, 0);
      __syncthreads();
    }
    {
      u16x8 ob;
      ob[0] = f2bf(q0.x); ob[1] = f2bf(q0.y); ob[2] = f2bf(q0.z); ob[3] = f2bf(q0.w);
      ob[4] = f2bf(q1.x); ob[5] = f2bf(q1.y); ob[6] = f2bf(q1.z); ob[7] = f2bf(q1.w);
      *(u16x8*)lBp = ob;
      async_copy16(gA0 + k0 + 32, lA0);
      async_copy16(gA1 + k0 + 32, lA1);
      __syncthreads();
      if (k0 + 96 < K) { q0 = *(const float4*)(gB + k0 + 96); q1 = *(const float4*)(gB + k0 + 100); }
      bf16x8 af[4], bg[2];
      #pragma unroll
      for (int mi = 0; mi < 4; ++mi) af[mi] = *(const bf16x8*)((const char*)As + aoff[mi]);
      #pragma unroll
      for (int nj = 0; nj < 2; ++nj) bg[nj] = *(const bf16x8*)((const char*)Bs + boff[nj]);
      #pragma unroll
      for (int mi = 0; mi < 4; ++mi)
        #pragma unroll
        for (int nj = 0; nj < 2; ++nj)
          acc[mi][nj] = __builtin_amdgcn_mfma_f32_16x16x32_bf16(af[mi], bg[nj], acc[mi][nj], 0, 0, 0);
      __syncthreads();
    }
  }

  #pragma unroll
  for (int mi = 0; mi < 4; ++mi) {
    #pragma unroll
    for (int nj = 0; nj < 2; ++nj) {
      int n = n0 + wc * 32 + nj * 16 + cl;
      if (n < N) {
        float bv = bias[n];
        #pragma unroll
        for (int j = 0; j < 4; ++j) {
          int m = wr * 64 + mi * 16 + q * 4 + j;
          C[(size_t)m * N + n] = acc[mi][nj][j] + bv;
        }
      }
    }
  }
}

// ---------------- small kernels ----------------
__global__ __launch_bounds__(256) void k_partial(const float* __restrict__ h,
    const float* __restrict__ W, const float* __restrict__ bias,
    float* __restrict__ out) {
  int b = blockIdx.y;
  int d = blockIdx.x * 256 + threadIdx.x;
  const float* hr = h + (size_t)b * DECD;
  float acc = bias[d];
  #pragma unroll 8
  for (int k = 0; k < DECD; ++k) acc += hr[k] * W[(size_t)k * DECD + d];
  out[(size_t)b * DECD + d] = acc;
}

__global__ __launch_bounds__(256) void k_softmax_s(float* __restrict__ sc, int S,
    const int* __restrict__ m1, const int* __restrict__ m2, int mode) {
  int b = blockIdx.x, tid = threadIdx.x;
  __shared__ float sm[4];
  int s0 = tid, s2 = tid + 256;
  float a0 = -INFINITY, a1 = -INFINITY;
  if (s0 < S) {
    int msk = (mode == 0) ? ((s0 < S1D) ? m1[b * S1D + s0] : m2[b * S2D + (s0 - S1D)])
                          : (m1[b * S1D + s0] * m2[b * S1D + s0]);
    a0 = msk ? sc[(size_t)b * S + s0] : NEGV;
  }
  if (s2 < S) {
    int msk = (mode == 0) ? ((s2 < S1D) ? m1[b * S1D + s2] : m2[b * S2D + (s2 - S1D)])
                          : (m1[b * S1D + s2] * m2[b * S1D + s2]);
    a1 = msk ? sc[(size_t)b * S + s2] : NEGV;
  }
  float vmax = fmaxf(a0, a1);
  #pragma unroll
  for (int off = 32; off > 0; off >>= 1) vmax = fmaxf(vmax, __shfl_down(vmax, off, 64));
  int lane = tid & 63, wid = tid >> 6;
  if (lane == 0) sm[wid] = vmax;
  __syncthreads();
  vmax = fmaxf(fmaxf(sm[0], sm[1]), fmaxf(sm[2], sm[3]));
  __syncthreads();
  float lsum = 0.f;
  if (s0 < S) lsum += expf(a0 - vmax);
  if (s2 < S) lsum += expf(a1 - vmax);
  #pragma unroll
  for (int off = 32; off > 0; off >>= 1) lsum += __shfl_down(lsum, off, 64);
  if (lane == 0) sm[wid] = lsum;
  __syncthreads();
  float inv = 1.0f / (sm[0] + sm[1] + sm[2] + sm[3]);
  if (s0 < S) sc[(size_t)b * S + s0] = expf(a0 - vmax) * inv;
  if (s2 < S) sc[(size_t)b * S + s2] = expf(a1 - vmax) * inv;
}

__global__ __launch_bounds__(256) void k_wpart(const u16* __restrict__ A,
    const float* __restrict__ a, float* __restrict__ wp) {
  int b = blockIdx.x;
  int e2 = blockIdx.y * 256 + threadIdx.x;
  int scn = blockIdx.z;
  const float* arow = a + (size_t)b * SJD;
  float acc0 = 0.f, acc1 = 0.f;
  #pragma unroll 4
  for (int s = scn * 100; s < scn * 100 + 100; ++s) {
    unsigned u = *(const unsigned*)(A + ((size_t)s * BB + b) * E2D + e2 * 2);
    float w = arow[s];
    acc0 += w * bf2f((u16)(u & 0xffff));
    acc1 += w * bf2f((u16)(u >> 16));
  }
  float* dst = wp + ((size_t)scn * BB + b) * E2D + e2 * 2;
  dst[0] = acc0;
  dst[1] = acc1;
}

__global__ __launch_bounds__(256) void k_wsum_x(const float* __restrict__ wp,
    float* __restrict__ wgt, u16* __restrict__ x) {
  int i = blockIdx.x * 256 + threadIdx.x;
  const int NN = BB * E2D;
  float s = wp[i] + wp[NN + i] + wp[2 * NN + i] + wp[3 * NN + i];
  wgt[i] = s;
  int b = i >> 10, e = i & 1023;
  x[(size_t)b * 1280 + EMBD + e] = f2bf(s);
}

__global__ __launch_bounds__(256) void k_embx(const int* __restrict__ inp,
    const float* __restrict__ table, u16* __restrict__ x) {
  int b = blockIdx.x, t = threadIdx.x;
  x[(size_t)b * 1280 + t] = f2bf(table[(size_t)inp[b] * EMBD + t]);
}

__global__ __launch_bounds__(256) void k_concat_state_bf(const float* __restrict__ hnew,
    const float* __restrict__ wgt, u16* __restrict__ st) {
  int b = blockIdx.x;
  for (int i = threadIdx.x; i < DECD + E2D; i += 256) {
    float vv = (i < DECD) ? hnew[(size_t)b * DECD + i] : wgt[(size_t)b * E2D + i - DECD];
    st[(size_t)b * (DECD + E2D) + i] = f2bf(vv);
  }
}

__global__ __launch_bounds__(256) void k_gru(const float* __restrict__ gx,
    const float* __restrict__ gh, const float* __restrict__ hidden,
    float* __restrict__ hnew) {
  int b = blockIdx.x, tid = threadIdx.x;
  #pragma unroll
  for (int qq = 0; qq < 2; ++qq) {
    int d = tid + qq * 256;
    size_t o = (size_t)b * 1536;
    float xr = gx[o + d],        hr = gh[o + d];
    float xz = gx[o + 512 + d],  hz = gh[o + 512 + d];
    float xn = gx[o + 1024 + d], hn = gh[o + 1024 + d];
    float r = 1.f / (1.f + expf(-(xr + hr)));
    float z = 1.f / (1.f + expf(-(xz + hz)));
    float n = tanhf(xn + r * hn);
    hnew[(size_t)b * DECD + d] = (1.f - z) * n + z * hidden[(size_t)b * DECD + d];
  }
}

__global__ __launch_bounds__(256) void k_pgen(const float* __restrict__ wgt,
    const int* __restrict__ inp, const float* __restrict__ table,
    const float* __restrict__ gW, const float* __restrict__ gb,
    float* __restrict__ pg) {
  int b = blockIdx.x, tid = threadIdx.x;
  __shared__ float sm[4];
  float s = 0.f;
  for (int k = tid; k < E2D + EMBD; k += 256)
    s += gW[k] * ((k < E2D) ? wgt[(size_t)b * E2D + k]
                            : table[(size_t)inp[b] * EMBD + k - E2D]);
  #pragma unroll
  for (int off = 32; off > 0; off >>= 1) s += __shfl_down(s, off, 64);
  int lane = tid & 63, wid = tid >> 6;
  if (lane == 0) sm[wid] = s;
  __syncthreads();
  if (tid == 0) {
    float t = sm[0] + sm[1] + sm[2] + sm[3] + gb[0];
    pg[b] = 1.f / (1.f + expf(-t));
  }
}

__global__ __launch_bounds__(256) void k_vocab(float* __restrict__ dist,
    const float* __restrict__ pg) {
  int b = blockIdx.x, tid = threadIdx.x;
  float* row = dist + (size_t)b * VV;
  __shared__ float sm[4];
  float m = -INFINITY;
  for (int i = tid; i < VV; i += 256) m = fmaxf(m, row[i]);
  #pragma unroll
  for (int off = 32; off > 0; off >>= 1) m = fmaxf(m, __shfl_down(m, off, 64));
  int lane = tid & 63, wid = tid >> 6;
  if (lane == 0) sm[wid] = m;
  __syncthreads();
  m = fmaxf(fmaxf(sm[0], sm[1]), fmaxf(sm[2], sm[3]));
  __syncthreads();
  float s = 0.f;
  for (int i = tid; i < VV; i += 256) s += expf(row[i] - m);
  #pragma unroll
  for (int off = 32; off > 0; off >>= 1) s += __shfl_down(s, off, 64);
  if (lane == 0) sm[wid] = s;
  __syncthreads();
  s = sm[0] + sm[1] + sm[2] + sm[3];
  float scale = pg[b] / s;
  for (int i = tid; i < VV; i += 256) row[i] = expf(row[i] - m) * scale;
}

__global__ __launch_bounds__(256) void k_scatter(float* __restrict__ dist,
    const float* __restrict__ ad, const float* __restrict__ pg,
    const int* __restrict__ src1) {
  int b = blockIdx.x, tid = threadIdx.x;
  if (tid < S1D) {
    float val = (1.f - pg[b]) * ad[(size_t)b * S1D + tid];
    int tok = src1[(size_t)tid * BB + b];
    atomicAdd(&dist[(size_t)b * VV + tok], val);
  }
}

extern "C" void kernel_launch(void* const* d_in, const int* in_sizes, int n_in,
                              void* d_out, int out_size, void* d_ws, size_t ws_size,
                              hipStream_t stream) {
  (void)in_sizes; (void)n_in; (void)out_size; (void)ws_size;
  const int*   input  = (const int*)d_in[0];
  const float* hidden = (const float*)d_in[1];
  const int*   src1   = (const int*)d_in[2];
  const float* enc1   = (const float*)d_in[3];
  const int*   mask1  = (const int*)d_in[4];
  const int*   triple = (const int*)d_in[5];
  const float* enc2   = (const float*)d_in[6];
  const int*   mask2  = (const int*)d_in[7];
  const float* embedding = (const float*)d_in[8];
  const float* attn_W = (const float*)d_in[9];
  const float* attn_b = (const float*)d_in[10];
  const float* attn_v = (const float*)d_in[11];
  const float* copy_W = (const float*)d_in[12];
  const float* copy_b = (const float*)d_in[13];
  const float* copy_v = (const float*)d_in[14];
  const float* gru_Wih = (const float*)d_in[15];
  const float* gru_Whh = (const float*)d_in[16];
  const float* gru_bih = (const float*)d_in[17];
  const float* gru_bhh = (const float*)d_in[18];
  const float* fc_W   = (const float*)d_in[19];
  const float* fc_b   = (const float*)d_in[20];
  const float* gate_W = (const float*)d_in[21];
  const float* gate_b = (const float*)d_in[22];

  char* w = (char*)d_ws;
  u16* A_bf = (u16*)w;                w += (size_t)51200 * 1024 * 2;
  u16* Wt_a = (u16*)w;                w += (size_t)512 * 1024 * 2;
  u16* Wt_c = (u16*)w;                w += (size_t)512 * 1024 * 2;
  float* partJ = (float*)w;           w += (size_t)2 * 51200 * 4;
  float* partC = (float*)w;           w += (size_t)2 * 25600 * 4;
  float* hWa  = (float*)w;            w += (size_t)BB * DECD * 4;
  float* hWc  = (float*)w;            w += (size_t)BB * DECD * 4;
  float* scJ  = (float*)w;            w += (size_t)BB * SJD * 4;
  float* scC  = (float*)w;            w += (size_t)BB * S1D * 4;
  float* wgt  = (float*)w;            w += (size_t)BB * E2D * 4;
  float* wpart = (float*)w;           w += (size_t)4 * BB * E2D * 4;
  u16*   x_bf = (u16*)w;              w += (size_t)BB * 1280 * 2;
  u16*   hid_bf = (u16*)w;            w += (size_t)BB * DECD * 2;
  float* gx   = (float*)w;            w += (size_t)BB * 1536 * 4;
  float* gh   = (float*)w;            w += (size_t)BB * 1536 * 4;
  u16*   st_bf = (u16*)w;             w += (size_t)BB * 1536 * 2;
  float* pg   = (float*)w;            w += 512;

  float* out  = (float*)d_out;
  float* hnew = out + (size_t)BB * VV;

  // prep
  k_wt<<<dim3(32, 16), 256, 0, stream>>>(attn_W, Wt_a);
  k_wt<<<dim3(32, 16), 256, 0, stream>>>(copy_W, Wt_c);
  k_cvt<<<32, 256, 0, stream>>>(hidden, hid_bf, BB * DECD / 8);
  k_partial<<<dim3(2, BB), 256, 0, stream>>>(hidden, attn_W, attn_b, hWa);
  k_embx<<<BB, 256, 0, stream>>>(input, embedding, x_bf);

  // joint attention scores (+ enc -> bf16 conversion side effect on n-half 0)
  gemm_energy4<1><<<dim3(2, SJD * 2), 256, 0, stream>>>(
      enc1, enc2, nullptr, A_bf, Wt_a, hWa, attn_v, partJ, 51200);
  k_sum2<<<200, 256, 0, stream>>>(partJ, scJ, 51200, SJD);
  k_softmax_s<<<BB, 256, 0, stream>>>(scJ, SJD, mask1, mask2, 0);

  // weighted context
  k_wpart<<<dim3(BB, 2, 4), 256, 0, stream>>>(A_bf, scJ, wpart);
  k_wsum_x<<<512, 256, 0, stream>>>(wpart, wgt, x_bf);

  // GRU (bf16 MFMA with fused weight conversion)
  gemm_fc<<<1536 / 64, 256, 0, stream>>>(x_bf, gru_Wih, gru_bih, gx, 1536, 1280);
  gemm_fc<<<1536 / 64, 256, 0, stream>>>(hid_bf, gru_Whh, gru_bhh, gh, 1536, 512);
  k_gru<<<BB, 256, 0, stream>>>(gx, gh, hidden, hnew);

  // vocab logits
  k_concat_state_bf<<<BB, 256, 0, stream>>>(hnew, wgt, st_bf);
  gemm_fc<<<(VV + 63) / 64, 256, 0, stream>>>(st_bf, fc_W, fc_b, out, VV, 1536);

  // copy path
  k_pgen<<<BB, 256, 0, stream>>>(wgt, input, embedding, gate_W, gate_b, pg);
  k_partial<<<dim3(2, BB), 256, 0, stream>>>(hnew, copy_W, copy_b, hWc);
  gemm_energy4<0><<<dim3(2, S1D * 2), 256, 0, stream>>>(
      nullptr, nullptr, A_bf, nullptr, Wt_c, hWc, copy_v, partC, 25600);
  k_sum2<<<100, 256, 0, stream>>>(partC, scC, 25600, S1D);
  k_softmax_s<<<BB, 256, 0, stream>>>(scC, S1D, mask1, triple, 1);

  // final distribution
  k_vocab<<<BB, 256, 0, stream>>>(out, pg);
  k_scatter<<<BB, 256, 0, stream>>>(out, scC, pg, src1);
}